// Round 1
// baseline (1949.586 us; speedup 1.0000x reference)
//
#include <hip/hip_runtime.h>

// ---------------- problem constants ----------------
#define T_TOK 8192          // B*S tokens
#define HID   2048
#define FFN_D 4096
#define NEXP  8
#define BM    128           // GEMM M tile (packed pair-rows)
#define BN    64            // GEMM N tile
#define BK    32            // GEMM K step (one mfma_16x16x32 K)
#define CAP_ROWS (T_TOK*2 + BM)          // 16512 (slack for last tile padding)
#define MAX_TILES (T_TOK*2/BM + NEXP)    // 136 worst-case M tiles
#define LDA 40              // padded LDS row stride in bf16 elems (80B -> conflict-light)

typedef unsigned short u16;
typedef unsigned int   u32;
typedef __attribute__((ext_vector_type(8))) u16    u16x8;
typedef __attribute__((ext_vector_type(8))) __bf16 bf16x8;
typedef __attribute__((ext_vector_type(4))) float  f32x4;

// meta[] int layout inside ws
#define M_CNT 0     // per-expert token count   [8]
#define M_CUR 8     // scatter cursor           [8]
#define M_OFF 16    // exclusive prefix offsets [8]
#define M_NT  24    // number of M tiles
#define M_TEXP 32   // tile -> expert           [MAX_TILES]
#define M_TM0  192  // tile -> first packed row [MAX_TILES]

__device__ __forceinline__ u16 f2bf(float f){   // RNE f32 -> bf16
  u32 u = __float_as_uint(f);
  u += 0x7FFFu + ((u >> 16) & 1u);
  return (u16)(u >> 16);
}

// ---------------- x -> bf16 ----------------
__global__ __launch_bounds__(256) void moe_cvtx(const float* __restrict__ x,
                                                u16* __restrict__ xb){
  size_t i = ((size_t)blockIdx.x * 256 + threadIdx.x) * 8;
  float4 v0 = *(const float4*)(x + i);
  float4 v1 = *(const float4*)(x + i + 4);
  u16x8 o;
  o[0]=f2bf(v0.x); o[1]=f2bf(v0.y); o[2]=f2bf(v0.z); o[3]=f2bf(v0.w);
  o[4]=f2bf(v1.x); o[5]=f2bf(v1.y); o[6]=f2bf(v1.z); o[7]=f2bf(v1.w);
  *(u16x8*)(xb + i) = o;
}

// ---------------- routing: one wave per token ----------------
__global__ __launch_bounds__(256) void moe_route(const float* __restrict__ x,
                                                 const float* __restrict__ gw,
                                                 int* __restrict__ meta,
                                                 int* __restrict__ tok_top,
                                                 float* __restrict__ tok_wt){
  const int wid  = threadIdx.x >> 6;
  const int lane = threadIdx.x & 63;
  const int tok  = blockIdx.x * 4 + wid;
  const float* xr = x + (size_t)tok * HID;

  float s[NEXP];
  #pragma unroll
  for (int e=0;e<NEXP;e++) s[e]=0.f;

  for (int k = lane*4; k < HID; k += 256){
    const float4 xv = *(const float4*)(xr + k);
    #pragma unroll
    for (int e=0;e<NEXP;e++){
      const float4 g = *(const float4*)(gw + e*HID + k);
      s[e] += xv.x*g.x + xv.y*g.y + xv.z*g.z + xv.w*g.w;
    }
  }
  #pragma unroll
  for (int o=32;o;o>>=1){
    #pragma unroll
    for (int e=0;e<NEXP;e++) s[e] += __shfl_xor(s[e], o);
  }
  if (lane==0){
    // top-1 (ties -> lowest index, matches jax top_k)
    float m1 = s[0]; int a = 0;
    #pragma unroll
    for (int e=1;e<NEXP;e++) if (s[e] > m1){ m1 = s[e]; a = e; }
    float m2 = -3.0e38f; int b = 0;
    #pragma unroll
    for (int e=0;e<NEXP;e++) if (e != a && s[e] > m2){ m2 = s[e]; b = e; }
    // renormalized top-2 softmax weights: wa = 1/(1+exp(l_b-l_a))
    const float r  = __expf(m2 - m1);
    const float wa = 1.f / (1.f + r);
    tok_top[tok*2]   = a;  tok_top[tok*2+1] = b;
    tok_wt[tok*2]    = wa; tok_wt[tok*2+1]  = r * wa;
    atomicAdd(&meta[M_CNT + a], 1);
    atomicAdd(&meta[M_CNT + b], 1);
  }
}

// ---------------- prefix + tile table (single thread, tiny) ----------------
__global__ void moe_prefix(int* __restrict__ meta){
  if (threadIdx.x != 0 || blockIdx.x != 0) return;
  int off = 0, nt = 0;
  for (int e=0;e<NEXP;e++){
    const int c = meta[M_CNT + e];
    meta[M_OFF + e] = off;
    meta[M_CUR + e] = off;
    const int ntE = (c + BM - 1) / BM;
    for (int i=0;i<ntE;i++){ meta[M_TEXP + nt] = e; meta[M_TM0 + nt] = off + i*BM; nt++; }
    off += c;
  }
  meta[M_NT] = nt;
}

// ---------------- scatter (token,k) -> packed rows ----------------
__global__ __launch_bounds__(256) void moe_scatter(const int* __restrict__ tok_top,
                                                   const float* __restrict__ tok_wt,
                                                   int* __restrict__ meta,
                                                   int* __restrict__ row_tok,
                                                   float* __restrict__ row_w){
  const int i = blockIdx.x * 256 + threadIdx.x;   // < T_TOK*2
  const int e = tok_top[i];
  const int pos = atomicAdd(&meta[M_CUR + e], 1);
  row_tok[pos] = i >> 1;
  row_w[pos]   = tok_wt[i];
}

// ---------------- up-GEMM: act = relu(x w1^T) * (x w3^T) * route_w ----------------
__global__ __launch_bounds__(256) void moe_up(const u16* __restrict__ xb,
                                              const float* __restrict__ w1,
                                              const float* __restrict__ w3,
                                              u16* __restrict__ act,
                                              const int* __restrict__ meta,
                                              const int* __restrict__ row_tok,
                                              const float* __restrict__ row_w){
  const int tile = blockIdx.y;
  if (tile >= meta[M_NT]) return;
  const int e      = meta[M_TEXP + tile];
  const int m0     = meta[M_TM0 + tile];
  const int rowEnd = meta[M_OFF + e] + meta[M_CNT + e];
  const int n0     = blockIdx.x * BN;

  const float* W1 = w1 + (size_t)e * FFN_D * HID;
  const float* W3 = w3 + (size_t)e * FFN_D * HID;

  __shared__ u16 As[BM * LDA];        // 10240 B
  __shared__ u16 Bs[2 * BN * LDA];    // 10240 B (w1 | w3)

  const int t    = threadIdx.x;
  const int wid  = t >> 6, lane = t & 63;
  const int wm   = wid >> 1, wn = wid & 1;

  // A staging: 512 16B units (128 rows x 4), 2 per thread; gather rows once
  const int ar0 = t >> 2, ac4 = t & 3;
  const int ar1 = 64 + ar0;
  const u16* asrc0 = xb + (size_t)row_tok[m0 + ar0] * HID + ac4 * 8;
  const u16* asrc1 = xb + (size_t)row_tok[m0 + ar1] * HID + ac4 * 8;
  // B staging: 64 rows x 4 8-float units, 1 per thread per matrix
  const int br = t >> 2, bc8 = t & 3;
  const float* b1src = W1 + (size_t)(n0 + br) * HID + bc8 * 8;
  const float* b3src = W3 + (size_t)(n0 + br) * HID + bc8 * 8;

  f32x4 accG[4][2], accU[4][2];
  #pragma unroll
  for (int i=0;i<4;i++){
    #pragma unroll
    for (int j=0;j<2;j++){ accG[i][j]=(f32x4)0.f; accU[i][j]=(f32x4)0.f; }
  }

  const int lr  = lane & 15;
  const int lk8 = (lane >> 4) * 8;

  for (int kk = 0; kk < HID; kk += BK){
    __syncthreads();
    *(u16x8*)(As + ar0*LDA + ac4*8) = *(const u16x8*)(asrc0 + kk);
    *(u16x8*)(As + ar1*LDA + ac4*8) = *(const u16x8*)(asrc1 + kk);
    {
      float4 v0 = *(const float4*)(b1src + kk);
      float4 v1 = *(const float4*)(b1src + kk + 4);
      u16x8 bv;
      bv[0]=f2bf(v0.x); bv[1]=f2bf(v0.y); bv[2]=f2bf(v0.z); bv[3]=f2bf(v0.w);
      bv[4]=f2bf(v1.x); bv[5]=f2bf(v1.y); bv[6]=f2bf(v1.z); bv[7]=f2bf(v1.w);
      *(u16x8*)(Bs + br*LDA + bc8*8) = bv;
      v0 = *(const float4*)(b3src + kk);
      v1 = *(const float4*)(b3src + kk + 4);
      bv[0]=f2bf(v0.x); bv[1]=f2bf(v0.y); bv[2]=f2bf(v0.z); bv[3]=f2bf(v0.w);
      bv[4]=f2bf(v1.x); bv[5]=f2bf(v1.y); bv[6]=f2bf(v1.z); bv[7]=f2bf(v1.w);
      *(u16x8*)(Bs + BN*LDA + br*LDA + bc8*8) = bv;
    }
    __syncthreads();

    bf16x8 a[4], bG[2], bU[2];
    #pragma unroll
    for (int mi=0;mi<4;mi++)
      a[mi] = *(const bf16x8*)(As + (wm*64 + mi*16 + lr)*LDA + lk8);
    #pragma unroll
    for (int ni=0;ni<2;ni++){
      bG[ni] = *(const bf16x8*)(Bs + (wn*32 + ni*16 + lr)*LDA + lk8);
      bU[ni] = *(const bf16x8*)(Bs + BN*LDA + (wn*32 + ni*16 + lr)*LDA + lk8);
    }
    #pragma unroll
    for (int mi=0;mi<4;mi++){
      #pragma unroll
      for (int ni=0;ni<2;ni++){
        accG[mi][ni] = __builtin_amdgcn_mfma_f32_16x16x32_bf16(a[mi], bG[ni], accG[mi][ni], 0,0,0);
        accU[mi][ni] = __builtin_amdgcn_mfma_f32_16x16x32_bf16(a[mi], bU[ni], accU[mi][ni], 0,0,0);
      }
    }
  }

  // epilogue: act[pos][n] = bf16(relu(g)*u*w)
  const int l4 = (lane >> 4) * 4;
  #pragma unroll
  for (int mi=0;mi<4;mi++){
    #pragma unroll
    for (int r=0;r<4;r++){
      const int pos = m0 + wm*64 + mi*16 + l4 + r;
      if (pos < rowEnd){
        const float rw = row_w[pos];
        #pragma unroll
        for (int ni=0;ni<2;ni++){
          const int n = n0 + wn*32 + ni*16 + lr;
          const float g = accG[mi][ni][r];
          const float u = accU[mi][ni][r];
          act[(size_t)pos * FFN_D + n] = f2bf(fmaxf(g, 0.f) * u * rw);
        }
      }
    }
  }
}

// ---------------- down-GEMM: out[tok] += act @ w2^T (route weight folded in act) ----------------
__global__ __launch_bounds__(256) void moe_down(const u16* __restrict__ act,
                                                const float* __restrict__ w2,
                                                float* __restrict__ out,
                                                const int* __restrict__ meta,
                                                const int* __restrict__ row_tok){
  const int tile = blockIdx.y;
  if (tile >= meta[M_NT]) return;
  const int e      = meta[M_TEXP + tile];
  const int m0     = meta[M_TM0 + tile];
  const int rowEnd = meta[M_OFF + e] + meta[M_CNT + e];
  const int n0     = blockIdx.x * BN;

  const float* W2 = w2 + (size_t)e * HID * FFN_D;

  __shared__ u16 As[BM * LDA];
  __shared__ u16 Bs[BN * LDA];

  const int t   = threadIdx.x;
  const int wid = t >> 6, lane = t & 63;
  const int wm  = wid >> 1, wn = wid & 1;

  const int ar0 = t >> 2, ac4 = t & 3;
  const int ar1 = 64 + ar0;
  const u16* asrc0 = act + (size_t)(m0 + ar0) * FFN_D + ac4 * 8;
  const u16* asrc1 = act + (size_t)(m0 + ar1) * FFN_D + ac4 * 8;
  const int br = t >> 2, bc8 = t & 3;
  const float* b2src = W2 + (size_t)(n0 + br) * FFN_D + bc8 * 8;

  f32x4 acc[4][2];
  #pragma unroll
  for (int i=0;i<4;i++){
    #pragma unroll
    for (int j=0;j<2;j++) acc[i][j]=(f32x4)0.f;
  }

  const int lr  = lane & 15;
  const int lk8 = (lane >> 4) * 8;

  for (int kk = 0; kk < FFN_D; kk += BK){
    __syncthreads();
    *(u16x8*)(As + ar0*LDA + ac4*8) = *(const u16x8*)(asrc0 + kk);
    *(u16x8*)(As + ar1*LDA + ac4*8) = *(const u16x8*)(asrc1 + kk);
    {
      float4 v0 = *(const float4*)(b2src + kk);
      float4 v1 = *(const float4*)(b2src + kk + 4);
      u16x8 bv;
      bv[0]=f2bf(v0.x); bv[1]=f2bf(v0.y); bv[2]=f2bf(v0.z); bv[3]=f2bf(v0.w);
      bv[4]=f2bf(v1.x); bv[5]=f2bf(v1.y); bv[6]=f2bf(v1.z); bv[7]=f2bf(v1.w);
      *(u16x8*)(Bs + br*LDA + bc8*8) = bv;
    }
    __syncthreads();

    bf16x8 a[4], b[2];
    #pragma unroll
    for (int mi=0;mi<4;mi++)
      a[mi] = *(const bf16x8*)(As + (wm*64 + mi*16 + lr)*LDA + lk8);
    #pragma unroll
    for (int ni=0;ni<2;ni++)
      b[ni] = *(const bf16x8*)(Bs + (wn*32 + ni*16 + lr)*LDA + lk8);
    #pragma unroll
    for (int mi=0;mi<4;mi++){
      #pragma unroll
      for (int ni=0;ni<2;ni++)
        acc[mi][ni] = __builtin_amdgcn_mfma_f32_16x16x32_bf16(a[mi], b[ni], acc[mi][ni], 0,0,0);
    }
  }

  const int l4 = (lane >> 4) * 4;
  #pragma unroll
  for (int mi=0;mi<4;mi++){
    #pragma unroll
    for (int r=0;r<4;r++){
      const int pos = m0 + wm*64 + mi*16 + l4 + r;
      if (pos < rowEnd){
        const int tok = row_tok[pos];
        #pragma unroll
        for (int ni=0;ni<2;ni++){
          const int n = n0 + wn*32 + ni*16 + lr;
          atomicAdd(out + (size_t)tok * HID + n, acc[mi][ni][r]);
        }
      }
    }
  }
}

// ---------------- host ----------------
extern "C" void kernel_launch(void* const* d_in, const int* in_sizes, int n_in,
                              void* d_out, int out_size, void* d_ws, size_t ws_size,
                              hipStream_t stream) {
  const float* x  = (const float*)d_in[0];   // [T, 2048]
  const float* gw = (const float*)d_in[1];   // [8, 2048]
  const float* w1 = (const float*)d_in[2];   // [8, 4096, 2048]
  const float* w2 = (const float*)d_in[3];   // [8, 2048, 4096]
  const float* w3 = (const float*)d_in[4];   // [8, 4096, 2048]
  float* out = (float*)d_out;

  // workspace layout
  const size_t OFF_ROWTOK = 4096;                               // meta ints in [0,4096)
  const size_t OFF_ROWW   = OFF_ROWTOK + (size_t)CAP_ROWS*4;    // 70144
  const size_t OFF_TOP    = OFF_ROWW  + (size_t)CAP_ROWS*4;     // 136192
  const size_t OFF_TOKW   = OFF_TOP   + (size_t)T_TOK*2*4;      // 201728
  const size_t OFF_XB     = OFF_TOKW  + (size_t)T_TOK*2*4;      // 267264 (16B aligned)
  const size_t OFF_ACT    = OFF_XB    + (size_t)T_TOK*HID*2;    // 33821696
  const size_t WS_NEED    = OFF_ACT   + (size_t)CAP_ROWS*FFN_D*2; // ~161.3 MiB
  if (ws_size < WS_NEED) return;   // loud failure: out stays poisoned/zeroed

  char* ws = (char*)d_ws;
  int*   meta    = (int*)ws;
  int*   row_tok = (int*)(ws + OFF_ROWTOK);
  float* row_w   = (float*)(ws + OFF_ROWW);
  int*   tok_top = (int*)(ws + OFF_TOP);
  float* tok_wt  = (float*)(ws + OFF_TOKW);
  u16*   xb      = (u16*)(ws + OFF_XB);
  u16*   act     = (u16*)(ws + OFF_ACT);

  hipMemsetAsync(d_out, 0, (size_t)T_TOK * HID * sizeof(float), stream);
  hipMemsetAsync(d_ws, 0, OFF_TOP, stream);   // meta + row_tok(+pad zeros) + row_w

  moe_cvtx   <<<dim3(T_TOK*HID/(256*8)), 256, 0, stream>>>(x, xb);
  moe_route  <<<dim3(T_TOK/4),           256, 0, stream>>>(x, gw, meta, tok_top, tok_wt);
  moe_prefix <<<1, 1, 0, stream>>>(meta);
  moe_scatter<<<dim3(T_TOK*2/256),       256, 0, stream>>>(tok_top, tok_wt, meta, row_tok, row_w);
  moe_up     <<<dim3(FFN_D/BN, MAX_TILES), 256, 0, stream>>>(xb, w1, w3, act, meta, row_tok, row_w);
  moe_down   <<<dim3(HID/BN,  MAX_TILES),  256, 0, stream>>>(act, w2, out, meta, row_tok);
}

// Round 2
// 1365.949 us; speedup vs baseline: 1.4273x; 1.4273x over previous
//
#include <hip/hip_runtime.h>

// ---------------- problem constants ----------------
#define T_TOK 8192          // B*S tokens
#define HID   2048
#define FFN_D 4096
#define NEXP  8
#define BM    128           // GEMM M tile (packed pair-rows)
#define CAP_ROWS (T_TOK*2 + BM)          // 16512
#define MAX_TILES (T_TOK*2/BM + NEXP)    // 136 worst-case M tiles
// slow-path tile params
#define BN    64
#define BK    32
#define LDA   40

typedef unsigned short u16;
typedef unsigned int   u32;
typedef __attribute__((ext_vector_type(8))) u16    u16x8;
typedef __attribute__((ext_vector_type(8))) __bf16 bf16x8;
typedef __attribute__((ext_vector_type(4))) float  f32x4;

// meta[] int layout inside ws
#define M_CNT 0
#define M_CUR 8
#define M_OFF 16
#define M_NT  24
#define M_TEXP 32
#define M_TM0  192

__device__ __forceinline__ u16 f2bf(float f){   // RNE f32 -> bf16
  u32 u = __float_as_uint(f);
  u += 0x7FFFu + ((u >> 16) & 1u);
  return (u16)(u >> 16);
}

__device__ __forceinline__ void gload16(const void* g, void* l){
  __builtin_amdgcn_global_load_lds((const __attribute__((address_space(1))) u32*)g,
                                   (__attribute__((address_space(3))) u32*)l, 16, 0, 0);
}

// ---------------- f32 -> bf16 stream convert (8 elems/thread) ----------------
__global__ __launch_bounds__(256) void moe_cvt(const float* __restrict__ src,
                                               u16* __restrict__ dst){
  size_t i = ((size_t)blockIdx.x * 256 + threadIdx.x) * 8;
  float4 v0 = *(const float4*)(src + i);
  float4 v1 = *(const float4*)(src + i + 4);
  u16x8 o;
  o[0]=f2bf(v0.x); o[1]=f2bf(v0.y); o[2]=f2bf(v0.z); o[3]=f2bf(v0.w);
  o[4]=f2bf(v1.x); o[5]=f2bf(v1.y); o[6]=f2bf(v1.z); o[7]=f2bf(v1.w);
  *(u16x8*)(dst + i) = o;
}

// ---------------- routing: one wave per token ----------------
__global__ __launch_bounds__(256) void moe_route(const float* __restrict__ x,
                                                 const float* __restrict__ gw,
                                                 int* __restrict__ meta,
                                                 int* __restrict__ tok_top,
                                                 float* __restrict__ tok_wt){
  const int wid  = threadIdx.x >> 6;
  const int lane = threadIdx.x & 63;
  const int tok  = blockIdx.x * 4 + wid;
  const float* xr = x + (size_t)tok * HID;

  float s[NEXP];
  #pragma unroll
  for (int e=0;e<NEXP;e++) s[e]=0.f;

  for (int k = lane*4; k < HID; k += 256){
    const float4 xv = *(const float4*)(xr + k);
    #pragma unroll
    for (int e=0;e<NEXP;e++){
      const float4 g = *(const float4*)(gw + e*HID + k);
      s[e] += xv.x*g.x + xv.y*g.y + xv.z*g.z + xv.w*g.w;
    }
  }
  #pragma unroll
  for (int o=32;o;o>>=1){
    #pragma unroll
    for (int e=0;e<NEXP;e++) s[e] += __shfl_xor(s[e], o);
  }
  if (lane==0){
    float m1 = s[0]; int a = 0;
    #pragma unroll
    for (int e=1;e<NEXP;e++) if (s[e] > m1){ m1 = s[e]; a = e; }
    float m2 = -3.0e38f; int b = 0;
    #pragma unroll
    for (int e=0;e<NEXP;e++) if (e != a && s[e] > m2){ m2 = s[e]; b = e; }
    const float r  = __expf(m2 - m1);
    const float wa = 1.f / (1.f + r);
    tok_top[tok*2]   = a;  tok_top[tok*2+1] = b;
    tok_wt[tok*2]    = wa; tok_wt[tok*2+1]  = r * wa;
    atomicAdd(&meta[M_CNT + a], 1);
    atomicAdd(&meta[M_CNT + b], 1);
  }
}

// ---------------- prefix + tile table ----------------
__global__ void moe_prefix(int* __restrict__ meta){
  if (threadIdx.x != 0 || blockIdx.x != 0) return;
  int off = 0, nt = 0;
  for (int e=0;e<NEXP;e++){
    const int c = meta[M_CNT + e];
    meta[M_OFF + e] = off;
    meta[M_CUR + e] = off;
    const int ntE = (c + BM - 1) / BM;
    for (int i=0;i<ntE;i++){ meta[M_TEXP + nt] = e; meta[M_TM0 + nt] = off + i*BM; nt++; }
    off += c;
  }
  meta[M_NT] = nt;
}

// ---------------- scatter ----------------
__global__ __launch_bounds__(256) void moe_scatter(const int* __restrict__ tok_top,
                                                   const float* __restrict__ tok_wt,
                                                   int* __restrict__ meta,
                                                   int* __restrict__ row_tok,
                                                   float* __restrict__ row_w){
  const int i = blockIdx.x * 256 + threadIdx.x;
  const int e = tok_top[i];
  const int pos = atomicAdd(&meta[M_CUR + e], 1);
  row_tok[pos] = i >> 1;
  row_w[pos]   = tok_wt[i];
}

// ================= FAST PATH (bf16 weights, global_load_lds, swizzled LDS) =================
// LDS tile layout: [rows][64] bf16, stored as 16B chunks; logical chunk c of row r
// lives at physical chunk pc = c ^ (r&7). Staged via pre-swizzled per-lane global src.

__global__ __launch_bounds__(256,2) void moe_up_f(
    const u16* __restrict__ xb, const u16* __restrict__ w1b, const u16* __restrict__ w3b,
    u16* __restrict__ act, const int* __restrict__ meta,
    const int* __restrict__ row_tok, const float* __restrict__ row_w){
  const int tile = blockIdx.y;
  if (tile >= meta[M_NT]) return;
  const int e      = meta[M_TEXP + tile];
  const int m0     = meta[M_TM0 + tile];
  const int rowEnd = meta[M_OFF + e] + meta[M_CNT + e];
  const int n0     = blockIdx.x * 64;

  __shared__ u16 As[128*64];     // 16 KB
  __shared__ u16 Bs[2*64*64];    // 16 KB (w1 | w3)

  const int t    = threadIdx.x;
  const int lane = t & 63;
  const int wid  = t >> 6;
  const int wm   = wid >> 1, wn = wid & 1;

  // pre-swizzled staging source offsets (elements)
  u32 aoff[4], boff[4];
  #pragma unroll
  for (int i=0;i<4;i++){
    const int g  = i*256 + t;        // chunk id 0..1023
    const int r  = g >> 3;           // 0..127
    const int pc = g & 7;
    aoff[i] = (u32)row_tok[m0 + r] * HID + (u32)((pc ^ (r & 7)) * 8);
    const int rr = r & 63;           // row within one B matrix
    boff[i] = (u32)(n0 + rr) * HID + (u32)((pc ^ (rr & 7)) * 8);
  }
  const size_t eW = (size_t)e * FFN_D * HID;
  const u16* w1e = w1b + eW;
  const u16* w3e = w3b + eW;

  f32x4 accG[4][2], accU[4][2];
  #pragma unroll
  for (int i=0;i<4;i++){
    #pragma unroll
    for (int j=0;j<2;j++){ accG[i][j]=(f32x4)0.f; accU[i][j]=(f32x4)0.f; }
  }

  const int lr = lane & 15;
  const int lq = lane >> 4;

  for (int kk = 0; kk < HID; kk += 64){
    __syncthreads();
    #pragma unroll
    for (int i=0;i<4;i++)
      gload16(xb + aoff[i] + kk, As + (size_t)(i*256 + wid*64)*8);
    gload16(w1e + boff[0] + kk, Bs + (size_t)(0*256 + wid*64)*8);
    gload16(w1e + boff[1] + kk, Bs + (size_t)(1*256 + wid*64)*8);
    gload16(w3e + boff[2] + kk, Bs + (size_t)(2*256 + wid*64)*8);
    gload16(w3e + boff[3] + kk, Bs + (size_t)(3*256 + wid*64)*8);
    __syncthreads();

    #pragma unroll
    for (int ks=0; ks<2; ks++){
      const int c = ks*4 + lq;
      bf16x8 a[4], bG[2], bU[2];
      #pragma unroll
      for (int mi=0;mi<4;mi++){
        const int r = wm*64 + mi*16 + lr;
        a[mi] = *(const bf16x8*)(As + r*64 + (c ^ (r&7))*8);
      }
      #pragma unroll
      for (int ni=0;ni<2;ni++){
        const int r  = wn*32 + ni*16 + lr;
        const int po = (c ^ (r&7))*8;
        bG[ni] = *(const bf16x8*)(Bs + r*64 + po);
        bU[ni] = *(const bf16x8*)(Bs + 4096 + r*64 + po);
      }
      #pragma unroll
      for (int mi=0;mi<4;mi++){
        #pragma unroll
        for (int ni=0;ni<2;ni++){
          accG[mi][ni] = __builtin_amdgcn_mfma_f32_16x16x32_bf16(a[mi], bG[ni], accG[mi][ni],0,0,0);
          accU[mi][ni] = __builtin_amdgcn_mfma_f32_16x16x32_bf16(a[mi], bU[ni], accU[mi][ni],0,0,0);
        }
      }
    }
  }

  const int l4 = lq * 4;
  #pragma unroll
  for (int mi=0;mi<4;mi++){
    #pragma unroll
    for (int r=0;r<4;r++){
      const int pos = m0 + wm*64 + mi*16 + l4 + r;
      if (pos < rowEnd){
        const float rw = row_w[pos];
        #pragma unroll
        for (int ni=0;ni<2;ni++){
          const int n = n0 + wn*32 + ni*16 + lr;
          const float g = accG[mi][ni][r];
          const float u = accU[mi][ni][r];
          act[(size_t)pos * FFN_D + n] = f2bf(fmaxf(g, 0.f) * u * rw);
        }
      }
    }
  }
}

__global__ __launch_bounds__(256,2) void moe_down_f(
    const u16* __restrict__ act, const u16* __restrict__ w2b,
    float* __restrict__ out, const int* __restrict__ meta,
    const int* __restrict__ row_tok){
  const int tile = blockIdx.y;
  if (tile >= meta[M_NT]) return;
  const int e      = meta[M_TEXP + tile];
  const int m0     = meta[M_TM0 + tile];
  const int rowEnd = meta[M_OFF + e] + meta[M_CNT + e];
  const int n0     = blockIdx.x * 128;

  __shared__ u16 As[128*64];   // 16 KB
  __shared__ u16 Bs[128*64];   // 16 KB

  const int t    = threadIdx.x;
  const int lane = t & 63;
  const int wid  = t >> 6;
  const int wm   = wid >> 1, wn = wid & 1;

  u32 aoff[4], boff[4];
  #pragma unroll
  for (int i=0;i<4;i++){
    const int g  = i*256 + t;
    const int r  = g >> 3;           // 0..127
    const int pc = g & 7;
    const int c8 = (pc ^ (r & 7)) * 8;
    aoff[i] = (u32)(m0 + r) * FFN_D + (u32)c8;
    boff[i] = (u32)(n0 + r) * FFN_D + (u32)c8;
  }
  const u16* w2e = w2b + (size_t)e * HID * FFN_D;

  f32x4 acc[4][4];
  #pragma unroll
  for (int i=0;i<4;i++){
    #pragma unroll
    for (int j=0;j<4;j++) acc[i][j]=(f32x4)0.f;
  }

  const int lr = lane & 15;
  const int lq = lane >> 4;

  for (int kk = 0; kk < FFN_D; kk += 64){
    __syncthreads();
    #pragma unroll
    for (int i=0;i<4;i++)
      gload16(act + aoff[i] + kk, As + (size_t)(i*256 + wid*64)*8);
    #pragma unroll
    for (int i=0;i<4;i++)
      gload16(w2e + boff[i] + kk, Bs + (size_t)(i*256 + wid*64)*8);
    __syncthreads();

    #pragma unroll
    for (int ks=0; ks<2; ks++){
      const int c = ks*4 + lq;
      bf16x8 a[4], b[4];
      #pragma unroll
      for (int mi=0;mi<4;mi++){
        const int r = wm*64 + mi*16 + lr;
        a[mi] = *(const bf16x8*)(As + r*64 + (c ^ (r&7))*8);
      }
      #pragma unroll
      for (int ni=0;ni<4;ni++){
        const int r = wn*64 + ni*16 + lr;
        b[ni] = *(const bf16x8*)(Bs + r*64 + (c ^ (r&7))*8);
      }
      #pragma unroll
      for (int mi=0;mi<4;mi++){
        #pragma unroll
        for (int ni=0;ni<4;ni++)
          acc[mi][ni] = __builtin_amdgcn_mfma_f32_16x16x32_bf16(a[mi], b[ni], acc[mi][ni],0,0,0);
      }
    }
  }

  const int l4 = lq * 4;
  #pragma unroll
  for (int mi=0;mi<4;mi++){
    #pragma unroll
    for (int r=0;r<4;r++){
      const int pos = m0 + wm*64 + mi*16 + l4 + r;
      if (pos < rowEnd){
        const int tok = row_tok[pos];
        #pragma unroll
        for (int ni=0;ni<4;ni++){
          const int n = n0 + wn*64 + ni*16 + lr;
          atomicAdd(out + (size_t)tok * HID + n, acc[mi][ni][r]);
        }
      }
    }
  }
}

// ================= SLOW PATH (f32 weights reg-staged; fallback if ws too small) =================
__global__ __launch_bounds__(256) void moe_up(const u16* __restrict__ xb,
                                              const float* __restrict__ w1,
                                              const float* __restrict__ w3,
                                              u16* __restrict__ act,
                                              const int* __restrict__ meta,
                                              const int* __restrict__ row_tok,
                                              const float* __restrict__ row_w){
  const int tile = blockIdx.y;
  if (tile >= meta[M_NT]) return;
  const int e      = meta[M_TEXP + tile];
  const int m0     = meta[M_TM0 + tile];
  const int rowEnd = meta[M_OFF + e] + meta[M_CNT + e];
  const int n0     = blockIdx.x * BN;

  const float* W1 = w1 + (size_t)e * FFN_D * HID;
  const float* W3 = w3 + (size_t)e * FFN_D * HID;

  __shared__ u16 As[BM * LDA];
  __shared__ u16 Bs[2 * BN * LDA];

  const int t    = threadIdx.x;
  const int wid  = t >> 6, lane = t & 63;
  const int wm   = wid >> 1, wn = wid & 1;

  const int ar0 = t >> 2, ac4 = t & 3;
  const int ar1 = 64 + ar0;
  const u16* asrc0 = xb + (size_t)row_tok[m0 + ar0] * HID + ac4 * 8;
  const u16* asrc1 = xb + (size_t)row_tok[m0 + ar1] * HID + ac4 * 8;
  const int br = t >> 2, bc8 = t & 3;
  const float* b1src = W1 + (size_t)(n0 + br) * HID + bc8 * 8;
  const float* b3src = W3 + (size_t)(n0 + br) * HID + bc8 * 8;

  f32x4 accG[4][2], accU[4][2];
  #pragma unroll
  for (int i=0;i<4;i++){
    #pragma unroll
    for (int j=0;j<2;j++){ accG[i][j]=(f32x4)0.f; accU[i][j]=(f32x4)0.f; }
  }

  const int lr  = lane & 15;
  const int lk8 = (lane >> 4) * 8;

  for (int kk = 0; kk < HID; kk += BK){
    __syncthreads();
    *(u16x8*)(As + ar0*LDA + ac4*8) = *(const u16x8*)(asrc0 + kk);
    *(u16x8*)(As + ar1*LDA + ac4*8) = *(const u16x8*)(asrc1 + kk);
    {
      float4 v0 = *(const float4*)(b1src + kk);
      float4 v1 = *(const float4*)(b1src + kk + 4);
      u16x8 bv;
      bv[0]=f2bf(v0.x); bv[1]=f2bf(v0.y); bv[2]=f2bf(v0.z); bv[3]=f2bf(v0.w);
      bv[4]=f2bf(v1.x); bv[5]=f2bf(v1.y); bv[6]=f2bf(v1.z); bv[7]=f2bf(v1.w);
      *(u16x8*)(Bs + br*LDA + bc8*8) = bv;
      v0 = *(const float4*)(b3src + kk);
      v1 = *(const float4*)(b3src + kk + 4);
      bv[0]=f2bf(v0.x); bv[1]=f2bf(v0.y); bv[2]=f2bf(v0.z); bv[3]=f2bf(v0.w);
      bv[4]=f2bf(v1.x); bv[5]=f2bf(v1.y); bv[6]=f2bf(v1.z); bv[7]=f2bf(v1.w);
      *(u16x8*)(Bs + BN*LDA + br*LDA + bc8*8) = bv;
    }
    __syncthreads();

    bf16x8 a[4], bG[2], bU[2];
    #pragma unroll
    for (int mi=0;mi<4;mi++)
      a[mi] = *(const bf16x8*)(As + (wm*64 + mi*16 + lr)*LDA + lk8);
    #pragma unroll
    for (int ni=0;ni<2;ni++){
      bG[ni] = *(const bf16x8*)(Bs + (wn*32 + ni*16 + lr)*LDA + lk8);
      bU[ni] = *(const bf16x8*)(Bs + BN*LDA + (wn*32 + ni*16 + lr)*LDA + lk8);
    }
    #pragma unroll
    for (int mi=0;mi<4;mi++){
      #pragma unroll
      for (int ni=0;ni<2;ni++){
        accG[mi][ni] = __builtin_amdgcn_mfma_f32_16x16x32_bf16(a[mi], bG[ni], accG[mi][ni], 0,0,0);
        accU[mi][ni] = __builtin_amdgcn_mfma_f32_16x16x32_bf16(a[mi], bU[ni], accU[mi][ni], 0,0,0);
      }
    }
  }

  const int l4 = (lane >> 4) * 4;
  #pragma unroll
  for (int mi=0;mi<4;mi++){
    #pragma unroll
    for (int r=0;r<4;r++){
      const int pos = m0 + wm*64 + mi*16 + l4 + r;
      if (pos < rowEnd){
        const float rw = row_w[pos];
        #pragma unroll
        for (int ni=0;ni<2;ni++){
          const int n = n0 + wn*32 + ni*16 + lr;
          const float g = accG[mi][ni][r];
          const float u = accU[mi][ni][r];
          act[(size_t)pos * FFN_D + n] = f2bf(fmaxf(g, 0.f) * u * rw);
        }
      }
    }
  }
}

__global__ __launch_bounds__(256) void moe_down(const u16* __restrict__ act,
                                                const float* __restrict__ w2,
                                                float* __restrict__ out,
                                                const int* __restrict__ meta,
                                                const int* __restrict__ row_tok){
  const int tile = blockIdx.y;
  if (tile >= meta[M_NT]) return;
  const int e      = meta[M_TEXP + tile];
  const int m0     = meta[M_TM0 + tile];
  const int rowEnd = meta[M_OFF + e] + meta[M_CNT + e];
  const int n0     = blockIdx.x * BN;

  const float* W2 = w2 + (size_t)e * HID * FFN_D;

  __shared__ u16 As[BM * LDA];
  __shared__ u16 Bs[BN * LDA];

  const int t   = threadIdx.x;
  const int wid = t >> 6, lane = t & 63;
  const int wm  = wid >> 1, wn = wid & 1;

  const int ar0 = t >> 2, ac4 = t & 3;
  const int ar1 = 64 + ar0;
  const u16* asrc0 = act + (size_t)(m0 + ar0) * FFN_D + ac4 * 8;
  const u16* asrc1 = act + (size_t)(m0 + ar1) * FFN_D + ac4 * 8;
  const int br = t >> 2, bc8 = t & 3;
  const float* b2src = W2 + (size_t)(n0 + br) * FFN_D + bc8 * 8;

  f32x4 acc[4][2];
  #pragma unroll
  for (int i=0;i<4;i++){
    #pragma unroll
    for (int j=0;j<2;j++) acc[i][j]=(f32x4)0.f;
  }

  const int lr  = lane & 15;
  const int lk8 = (lane >> 4) * 8;

  for (int kk = 0; kk < FFN_D; kk += BK){
    __syncthreads();
    *(u16x8*)(As + ar0*LDA + ac4*8) = *(const u16x8*)(asrc0 + kk);
    *(u16x8*)(As + ar1*LDA + ac4*8) = *(const u16x8*)(asrc1 + kk);
    {
      float4 v0 = *(const float4*)(b2src + kk);
      float4 v1 = *(const float4*)(b2src + kk + 4);
      u16x8 bv;
      bv[0]=f2bf(v0.x); bv[1]=f2bf(v0.y); bv[2]=f2bf(v0.z); bv[3]=f2bf(v0.w);
      bv[4]=f2bf(v1.x); bv[5]=f2bf(v1.y); bv[6]=f2bf(v1.z); bv[7]=f2bf(v1.w);
      *(u16x8*)(Bs + br*LDA + bc8*8) = bv;
    }
    __syncthreads();

    bf16x8 a[4], b[2];
    #pragma unroll
    for (int mi=0;mi<4;mi++)
      a[mi] = *(const bf16x8*)(As + (wm*64 + mi*16 + lr)*LDA + lk8);
    #pragma unroll
    for (int ni=0;ni<2;ni++)
      b[ni] = *(const bf16x8*)(Bs + (wn*32 + ni*16 + lr)*LDA + lk8);
    #pragma unroll
    for (int mi=0;mi<4;mi++){
      #pragma unroll
      for (int ni=0;ni<2;ni++)
        acc[mi][ni] = __builtin_amdgcn_mfma_f32_16x16x32_bf16(a[mi], b[ni], acc[mi][ni], 0,0,0);
    }
  }

  const int l4 = (lane >> 4) * 4;
  #pragma unroll
  for (int mi=0;mi<4;mi++){
    #pragma unroll
    for (int r=0;r<4;r++){
      const int pos = m0 + wm*64 + mi*16 + l4 + r;
      if (pos < rowEnd){
        const int tok = row_tok[pos];
        #pragma unroll
        for (int ni=0;ni<2;ni++){
          const int n = n0 + wn*32 + ni*16 + lr;
          atomicAdd(out + (size_t)tok * HID + n, acc[mi][ni][r]);
        }
      }
    }
  }
}

// ---------------- host ----------------
extern "C" void kernel_launch(void* const* d_in, const int* in_sizes, int n_in,
                              void* d_out, int out_size, void* d_ws, size_t ws_size,
                              hipStream_t stream) {
  const float* x  = (const float*)d_in[0];
  const float* gw = (const float*)d_in[1];
  const float* w1 = (const float*)d_in[2];
  const float* w2 = (const float*)d_in[3];
  const float* w3 = (const float*)d_in[4];
  float* out = (float*)d_out;

  // common small buffers
  const size_t OFF_ROWTOK = 4096;
  const size_t OFF_ROWW   = OFF_ROWTOK + (size_t)CAP_ROWS*4;      // 70144
  const size_t OFF_TOP    = OFF_ROWW  + (size_t)CAP_ROWS*4;       // 136192
  const size_t OFF_TOKW   = OFF_TOP   + (size_t)T_TOK*2*4;        // 201728
  const size_t OFF_XB     = OFF_TOKW  + (size_t)T_TOK*2*4;        // 267264
  const size_t XB_BYTES   = (size_t)T_TOK*HID*2;                  // 33.55 MB
  // fast layout
  const size_t WB       = (size_t)NEXP*FFN_D*HID*2;               // 134.2 MB per weight
  const size_t OFF_W1B  = OFF_XB  + XB_BYTES;
  const size_t OFF_W3B  = OFF_W1B + WB;
  const size_t OFF_ACTF = OFF_W3B + WB;
  const size_t WS_FAST  = OFF_ACTF + (size_t)CAP_ROWS*FFN_D*2;    // ~437.5 MB
  // slow layout
  const size_t OFF_ACTS = OFF_XB + XB_BYTES;
  const size_t WS_SLOW  = OFF_ACTS + (size_t)CAP_ROWS*FFN_D*2;    // ~161.3 MB

  char* ws = (char*)d_ws;
  int*   meta    = (int*)ws;
  int*   row_tok = (int*)(ws + OFF_ROWTOK);
  float* row_w   = (float*)(ws + OFF_ROWW);
  int*   tok_top = (int*)(ws + OFF_TOP);
  float* tok_wt  = (float*)(ws + OFF_TOKW);
  u16*   xb      = (u16*)(ws + OFF_XB);

  hipMemsetAsync(d_out, 0, (size_t)T_TOK * HID * sizeof(float), stream);
  hipMemsetAsync(d_ws, 0, OFF_TOP, stream);

  moe_cvt    <<<dim3(T_TOK*HID/2048), 256, 0, stream>>>(x, xb);
  moe_route  <<<dim3(T_TOK/4),        256, 0, stream>>>(x, gw, meta, tok_top, tok_wt);
  moe_prefix <<<1, 1, 0, stream>>>(meta);
  moe_scatter<<<dim3(T_TOK*2/256),    256, 0, stream>>>(tok_top, tok_wt, meta, row_tok, row_w);

  if (ws_size >= WS_FAST){
    u16* w1b = (u16*)(ws + OFF_W1B);     // also reused for w2b after moe_up_f
    u16* w3b = (u16*)(ws + OFF_W3B);
    u16* act = (u16*)(ws + OFF_ACTF);
    const int WCVT = (int)(NEXP*(size_t)FFN_D*HID/2048);   // 32768 blocks
    moe_cvt   <<<dim3(WCVT), 256, 0, stream>>>(w1, w1b);
    moe_cvt   <<<dim3(WCVT), 256, 0, stream>>>(w3, w3b);
    moe_up_f  <<<dim3(FFN_D/64, MAX_TILES), 256, 0, stream>>>(xb, w1b, w3b, act, meta, row_tok, row_w);
    moe_cvt   <<<dim3(WCVT), 256, 0, stream>>>(w2, w1b);   // w2b aliases w1b slot
    moe_down_f<<<dim3(HID/128, MAX_TILES),  256, 0, stream>>>(act, w1b, out, meta, row_tok);
  } else if (ws_size >= WS_SLOW){
    u16* act = (u16*)(ws + OFF_ACTS);
    moe_up   <<<dim3(FFN_D/BN, MAX_TILES), 256, 0, stream>>>(xb, w1, w3, act, meta, row_tok, row_w);
    moe_down <<<dim3(HID/BN,  MAX_TILES),  256, 0, stream>>>(act, w2, out, meta, row_tok);
  }
}

// Round 3
// 1341.230 us; speedup vs baseline: 1.4536x; 1.0184x over previous
//
#include <hip/hip_runtime.h>

// ---------------- problem constants ----------------
#define T_TOK 8192          // B*S tokens
#define HID   2048
#define FFN_D 4096
#define NEXP  8
#define BM    128           // GEMM M tile (packed pair-rows)
#define CAP_ROWS (T_TOK*2 + BM)          // 16512
#define MAX_TILES (T_TOK*2/BM + NEXP)    // 136 worst-case M tiles

typedef unsigned short u16;
typedef unsigned int   u32;
typedef __attribute__((ext_vector_type(8))) u16    u16x8;
typedef __attribute__((ext_vector_type(8))) __bf16 bf16x8;
typedef __attribute__((ext_vector_type(4))) float  f32x4;

// meta[] int layout inside ws
#define M_CNT 0
#define M_CUR 8
#define M_OFF 16
#define M_NT  24
#define M_TEXP 32
#define M_TM0  192

__device__ __forceinline__ u16 f2bf(float f){   // RNE f32 -> bf16
  u32 u = __float_as_uint(f);
  u += 0x7FFFu + ((u >> 16) & 1u);
  return (u16)(u >> 16);
}
__device__ __forceinline__ float bf2f(u16 v){
  return __uint_as_float(((u32)v) << 16);
}

__device__ __forceinline__ void gload16(const void* g, void* l){
  __builtin_amdgcn_global_load_lds((const __attribute__((address_space(1))) u32*)g,
                                   (__attribute__((address_space(3))) u32*)l, 16, 0, 0);
}

// ---------------- f32 -> bf16 stream convert (8 elems/thread) ----------------
__global__ __launch_bounds__(256) void moe_cvt(const float* __restrict__ src,
                                               u16* __restrict__ dst){
  size_t i = ((size_t)blockIdx.x * 256 + threadIdx.x) * 8;
  float4 v0 = *(const float4*)(src + i);
  float4 v1 = *(const float4*)(src + i + 4);
  u16x8 o;
  o[0]=f2bf(v0.x); o[1]=f2bf(v0.y); o[2]=f2bf(v0.z); o[3]=f2bf(v0.w);
  o[4]=f2bf(v1.x); o[5]=f2bf(v1.y); o[6]=f2bf(v1.z); o[7]=f2bf(v1.w);
  *(u16x8*)(dst + i) = o;
}

// ---------------- routing: one wave per token ----------------
__global__ __launch_bounds__(256) void moe_route(const float* __restrict__ x,
                                                 const float* __restrict__ gw,
                                                 int* __restrict__ meta,
                                                 int* __restrict__ tok_top,
                                                 float* __restrict__ tok_wt){
  const int wid  = threadIdx.x >> 6;
  const int lane = threadIdx.x & 63;
  const int tok  = blockIdx.x * 4 + wid;
  const float* xr = x + (size_t)tok * HID;

  float s[NEXP];
  #pragma unroll
  for (int e=0;e<NEXP;e++) s[e]=0.f;

  for (int k = lane*4; k < HID; k += 256){
    const float4 xv = *(const float4*)(xr + k);
    #pragma unroll
    for (int e=0;e<NEXP;e++){
      const float4 g = *(const float4*)(gw + e*HID + k);
      s[e] += xv.x*g.x + xv.y*g.y + xv.z*g.z + xv.w*g.w;
    }
  }
  #pragma unroll
  for (int o=32;o;o>>=1){
    #pragma unroll
    for (int e=0;e<NEXP;e++) s[e] += __shfl_xor(s[e], o);
  }
  if (lane==0){
    float m1 = s[0]; int a = 0;
    #pragma unroll
    for (int e=1;e<NEXP;e++) if (s[e] > m1){ m1 = s[e]; a = e; }
    float m2 = -3.0e38f; int b = 0;
    #pragma unroll
    for (int e=0;e<NEXP;e++) if (e != a && s[e] > m2){ m2 = s[e]; b = e; }
    const float r  = __expf(m2 - m1);
    const float wa = 1.f / (1.f + r);
    tok_top[tok*2]   = a;  tok_top[tok*2+1] = b;
    tok_wt[tok*2]    = wa; tok_wt[tok*2+1]  = r * wa;
    atomicAdd(&meta[M_CNT + a], 1);
    atomicAdd(&meta[M_CNT + b], 1);
  }
}

// ---------------- prefix + tile table ----------------
__global__ void moe_prefix(int* __restrict__ meta){
  if (threadIdx.x != 0 || blockIdx.x != 0) return;
  int off = 0, nt = 0;
  for (int e=0;e<NEXP;e++){
    const int c = meta[M_CNT + e];
    meta[M_OFF + e] = off;
    meta[M_CUR + e] = off;
    const int ntE = (c + BM - 1) / BM;
    for (int i=0;i<ntE;i++){ meta[M_TEXP + nt] = e; meta[M_TM0 + nt] = off + i*BM; nt++; }
    off += c;
  }
  meta[M_NT] = nt;
}

// ---------------- scatter (also records inverse map pos_of, aliased on tok_wt) ----------------
__global__ __launch_bounds__(256) void moe_scatter(const int* __restrict__ tok_top,
                                                   float* __restrict__ tok_wt,
                                                   int* __restrict__ meta,
                                                   int* __restrict__ row_tok,
                                                   float* __restrict__ row_w){
  const int i = blockIdx.x * 256 + threadIdx.x;
  const int e = tok_top[i];
  const float w = tok_wt[i];
  const int pos = atomicAdd(&meta[M_CUR + e], 1);
  row_tok[pos] = i >> 1;
  row_w[pos]   = w;
  ((int*)tok_wt)[i] = pos;      // pos_of: safe self-alias (own slot, after read)
}

// ================= up-GEMM (bf16 weights, global_load_lds, swizzled LDS) =================
// LDS tile layout: [rows][64] bf16 in 16B chunks; logical chunk c of row r at pc = c ^ (r&7).

__global__ __launch_bounds__(256,2) void moe_up_f(
    const u16* __restrict__ xb, const u16* __restrict__ w1b, const u16* __restrict__ w3b,
    u16* __restrict__ act, const int* __restrict__ meta,
    const int* __restrict__ row_tok, const float* __restrict__ row_w){
  const int tile = blockIdx.y;
  if (tile >= meta[M_NT]) return;
  const int e      = meta[M_TEXP + tile];
  const int m0     = meta[M_TM0 + tile];
  const int rowEnd = meta[M_OFF + e] + meta[M_CNT + e];
  const int n0     = blockIdx.x * 64;

  __shared__ u16 As[128*64];     // 16 KB
  __shared__ u16 Bs[2*64*64];    // 16 KB (w1 | w3)

  const int t    = threadIdx.x;
  const int lane = t & 63;
  const int wid  = t >> 6;
  const int wm   = wid >> 1, wn = wid & 1;

  u32 aoff[4], boff[4];
  #pragma unroll
  for (int i=0;i<4;i++){
    const int g  = i*256 + t;        // chunk id 0..1023
    const int r  = g >> 3;           // 0..127
    const int pc = g & 7;
    aoff[i] = (u32)row_tok[m0 + r] * HID + (u32)((pc ^ (r & 7)) * 8);
    const int rr = r & 63;
    boff[i] = (u32)(n0 + rr) * HID + (u32)((pc ^ (rr & 7)) * 8);
  }
  const size_t eW = (size_t)e * FFN_D * HID;
  const u16* w1e = w1b + eW;
  const u16* w3e = w3b + eW;

  f32x4 accG[4][2], accU[4][2];
  #pragma unroll
  for (int i=0;i<4;i++){
    #pragma unroll
    for (int j=0;j<2;j++){ accG[i][j]=(f32x4)0.f; accU[i][j]=(f32x4)0.f; }
  }

  const int lr = lane & 15;
  const int lq = lane >> 4;

  for (int kk = 0; kk < HID; kk += 64){
    __syncthreads();
    #pragma unroll
    for (int i=0;i<4;i++)
      gload16(xb + aoff[i] + kk, As + (size_t)(i*256 + wid*64)*8);
    gload16(w1e + boff[0] + kk, Bs + (size_t)(0*256 + wid*64)*8);
    gload16(w1e + boff[1] + kk, Bs + (size_t)(1*256 + wid*64)*8);
    gload16(w3e + boff[2] + kk, Bs + (size_t)(2*256 + wid*64)*8);
    gload16(w3e + boff[3] + kk, Bs + (size_t)(3*256 + wid*64)*8);
    __syncthreads();

    #pragma unroll
    for (int ks=0; ks<2; ks++){
      const int c = ks*4 + lq;
      bf16x8 a[4], bG[2], bU[2];
      #pragma unroll
      for (int mi=0;mi<4;mi++){
        const int r = wm*64 + mi*16 + lr;
        a[mi] = *(const bf16x8*)(As + r*64 + (c ^ (r&7))*8);
      }
      #pragma unroll
      for (int ni=0;ni<2;ni++){
        const int r  = wn*32 + ni*16 + lr;
        const int po = (c ^ (r&7))*8;
        bG[ni] = *(const bf16x8*)(Bs + r*64 + po);
        bU[ni] = *(const bf16x8*)(Bs + 4096 + r*64 + po);
      }
      #pragma unroll
      for (int mi=0;mi<4;mi++){
        #pragma unroll
        for (int ni=0;ni<2;ni++){
          accG[mi][ni] = __builtin_amdgcn_mfma_f32_16x16x32_bf16(a[mi], bG[ni], accG[mi][ni],0,0,0);
          accU[mi][ni] = __builtin_amdgcn_mfma_f32_16x16x32_bf16(a[mi], bU[ni], accU[mi][ni],0,0,0);
        }
      }
    }
  }

  const int l4 = lq * 4;
  #pragma unroll
  for (int mi=0;mi<4;mi++){
    #pragma unroll
    for (int r=0;r<4;r++){
      const int pos = m0 + wm*64 + mi*16 + l4 + r;
      if (pos < rowEnd){
        const float rw = row_w[pos];
        #pragma unroll
        for (int ni=0;ni<2;ni++){
          const int n = n0 + wn*32 + ni*16 + lr;
          const float g = accG[mi][ni][r];
          const float u = accU[mi][ni][r];
          act[(size_t)pos * FFN_D + n] = f2bf(fmaxf(g, 0.f) * u * rw);
        }
      }
    }
  }
}

// ================= down-GEMM: part[pos] = act[pos] @ w2^T (NO atomics) =================
__global__ __launch_bounds__(256,2) void moe_down_f(
    const u16* __restrict__ act, const u16* __restrict__ w2b,
    u16* __restrict__ part, const int* __restrict__ meta){
  const int tile = blockIdx.y;
  if (tile >= meta[M_NT]) return;
  const int e      = meta[M_TEXP + tile];
  const int m0     = meta[M_TM0 + tile];
  const int rowEnd = meta[M_OFF + e] + meta[M_CNT + e];
  const int n0     = blockIdx.x * 128;

  __shared__ u16 As[128*64];   // 16 KB
  __shared__ u16 Bs[128*64];   // 16 KB

  const int t    = threadIdx.x;
  const int lane = t & 63;
  const int wid  = t >> 6;
  const int wm   = wid >> 1, wn = wid & 1;

  u32 aoff[4], boff[4];
  #pragma unroll
  for (int i=0;i<4;i++){
    const int g  = i*256 + t;
    const int r  = g >> 3;           // 0..127
    const int pc = g & 7;
    const int c8 = (pc ^ (r & 7)) * 8;
    aoff[i] = (u32)(m0 + r) * FFN_D + (u32)c8;
    boff[i] = (u32)(n0 + r) * FFN_D + (u32)c8;
  }
  const u16* w2e = w2b + (size_t)e * HID * FFN_D;

  f32x4 acc[4][4];
  #pragma unroll
  for (int i=0;i<4;i++){
    #pragma unroll
    for (int j=0;j<4;j++) acc[i][j]=(f32x4)0.f;
  }

  const int lr = lane & 15;
  const int lq = lane >> 4;

  for (int kk = 0; kk < FFN_D; kk += 64){
    __syncthreads();
    #pragma unroll
    for (int i=0;i<4;i++)
      gload16(act + aoff[i] + kk, As + (size_t)(i*256 + wid*64)*8);
    #pragma unroll
    for (int i=0;i<4;i++)
      gload16(w2e + boff[i] + kk, Bs + (size_t)(i*256 + wid*64)*8);
    __syncthreads();

    #pragma unroll
    for (int ks=0; ks<2; ks++){
      const int c = ks*4 + lq;
      bf16x8 a[4], b[4];
      #pragma unroll
      for (int mi=0;mi<4;mi++){
        const int r = wm*64 + mi*16 + lr;
        a[mi] = *(const bf16x8*)(As + r*64 + (c ^ (r&7))*8);
      }
      #pragma unroll
      for (int ni=0;ni<4;ni++){
        const int r = wn*64 + ni*16 + lr;
        b[ni] = *(const bf16x8*)(Bs + r*64 + (c ^ (r&7))*8);
      }
      #pragma unroll
      for (int mi=0;mi<4;mi++){
        #pragma unroll
        for (int ni=0;ni<4;ni++)
          acc[mi][ni] = __builtin_amdgcn_mfma_f32_16x16x32_bf16(a[mi], b[ni], acc[mi][ni],0,0,0);
      }
    }
  }

  const int l4 = lq * 4;
  #pragma unroll
  for (int mi=0;mi<4;mi++){
    #pragma unroll
    for (int r=0;r<4;r++){
      const int pos = m0 + wm*64 + mi*16 + l4 + r;
      if (pos < rowEnd){
        u16* prow = part + (size_t)pos * HID;
        #pragma unroll
        for (int ni=0;ni<4;ni++){
          const int n = n0 + wn*64 + ni*16 + lr;
          prow[n] = f2bf(acc[mi][ni][r]);
        }
      }
    }
  }
}

// ---------------- combine: out[tok] = part[p0] + part[p1] ----------------
__global__ __launch_bounds__(256) void moe_combine(const u16* __restrict__ part,
                                                   const int* __restrict__ pos_of,
                                                   float* __restrict__ out){
  const int tok = blockIdx.x;
  const int p0 = pos_of[tok*2];
  const int p1 = pos_of[tok*2+1];
  const int h = threadIdx.x * 8;
  const u16x8 a = *(const u16x8*)(part + (size_t)p0 * HID + h);
  const u16x8 b = *(const u16x8*)(part + (size_t)p1 * HID + h);
  float4 o0, o1;
  o0.x = bf2f(a[0]) + bf2f(b[0]);
  o0.y = bf2f(a[1]) + bf2f(b[1]);
  o0.z = bf2f(a[2]) + bf2f(b[2]);
  o0.w = bf2f(a[3]) + bf2f(b[3]);
  o1.x = bf2f(a[4]) + bf2f(b[4]);
  o1.y = bf2f(a[5]) + bf2f(b[5]);
  o1.z = bf2f(a[6]) + bf2f(b[6]);
  o1.w = bf2f(a[7]) + bf2f(b[7]);
  float* orow = out + (size_t)tok * HID + h;
  *(float4*)orow = o0;
  *(float4*)(orow + 4) = o1;
}

// ---------------- host ----------------
extern "C" void kernel_launch(void* const* d_in, const int* in_sizes, int n_in,
                              void* d_out, int out_size, void* d_ws, size_t ws_size,
                              hipStream_t stream) {
  const float* x  = (const float*)d_in[0];
  const float* gw = (const float*)d_in[1];
  const float* w1 = (const float*)d_in[2];
  const float* w2 = (const float*)d_in[3];
  const float* w3 = (const float*)d_in[4];
  float* out = (float*)d_out;

  // layout (unchanged from round 2 fast path)
  const size_t OFF_ROWTOK = 4096;
  const size_t OFF_ROWW   = OFF_ROWTOK + (size_t)CAP_ROWS*4;      // 70144
  const size_t OFF_TOP    = OFF_ROWW  + (size_t)CAP_ROWS*4;       // 136192
  const size_t OFF_TOKW   = OFF_TOP   + (size_t)T_TOK*2*4;        // 201728
  const size_t OFF_XB     = OFF_TOKW  + (size_t)T_TOK*2*4;        // 267264
  const size_t XB_BYTES   = (size_t)T_TOK*HID*2;                  // 33.55 MB
  const size_t WB       = (size_t)NEXP*FFN_D*HID*2;               // 134.2 MB
  const size_t OFF_W1B  = OFF_XB  + XB_BYTES;
  const size_t OFF_W3B  = OFF_W1B + WB;       // w3b; also 'part' after moe_up_f
  const size_t OFF_ACTF = OFF_W3B + WB;
  const size_t WS_FAST  = OFF_ACTF + (size_t)CAP_ROWS*FFN_D*2;    // ~437.5 MB
  if (ws_size < WS_FAST) return;

  char* ws = (char*)d_ws;
  int*   meta    = (int*)ws;
  int*   row_tok = (int*)(ws + OFF_ROWTOK);
  float* row_w   = (float*)(ws + OFF_ROWW);
  int*   tok_top = (int*)(ws + OFF_TOP);
  float* tok_wt  = (float*)(ws + OFF_TOKW);   // pos_of aliases this after scatter
  u16*   xb      = (u16*)(ws + OFF_XB);
  u16*   w1b     = (u16*)(ws + OFF_W1B);      // w2b reuses this slot after up
  u16*   w3b     = (u16*)(ws + OFF_W3B);      // part reuses this slot after up
  u16*   act     = (u16*)(ws + OFF_ACTF);

  hipMemsetAsync(d_ws, 0, OFF_TOP, stream);   // meta + row_tok + row_w

  moe_cvt    <<<dim3(T_TOK*HID/2048), 256, 0, stream>>>(x, xb);
  moe_route  <<<dim3(T_TOK/4),        256, 0, stream>>>(x, gw, meta, tok_top, tok_wt);
  moe_prefix <<<1, 1, 0, stream>>>(meta);
  moe_scatter<<<dim3(T_TOK*2/256),    256, 0, stream>>>(tok_top, tok_wt, meta, row_tok, row_w);

  const int WCVT = (int)(NEXP*(size_t)FFN_D*HID/2048);   // 32768 blocks
  moe_cvt   <<<dim3(WCVT), 256, 0, stream>>>(w1, w1b);
  moe_cvt   <<<dim3(WCVT), 256, 0, stream>>>(w3, w3b);
  moe_up_f  <<<dim3(FFN_D/64, MAX_TILES), 256, 0, stream>>>(xb, w1b, w3b, act, meta, row_tok, row_w);

  u16* part = w3b;                                       // w3b dead after up
  moe_cvt   <<<dim3(WCVT), 256, 0, stream>>>(w2, w1b);   // w2b aliases w1b
  moe_down_f<<<dim3(HID/128, MAX_TILES),  256, 0, stream>>>(act, w1b, part, meta);
  moe_combine<<<dim3(T_TOK), 256, 0, stream>>>(part, (const int*)tok_wt, out);
}